// Round 7
// baseline (290.403 us; speedup 1.0000x reference)
//
#include <hip/hip_runtime.h>
#include <hip/hip_bf16.h>

// BERT_SCL: loss = 0.9 * supcon(cls_emb, labels) + 0.1 * CE(pooled@W.T + b, labels)
// d_out[0] = loss, d_out[1..57344] = logits (8192 x 7, f32)
//
// e8 = fp8_e4m3( row-normalized cls * 1/sqrt(TEMP) ).  S8_ij = e8_i . e8_j.
// Fixed-max logsumexp (S <= M = 1/TEMP). possum_i = e8_i.T_{l_i} - ||e8_i||^2
// (positive mask linear in S) -> big MFMA kernel computes ONLY exp-sums.
// BOTH lse and possum use the SAME quantized e8 -> quantization shift cancels
// to first order in per_anchor = lse - possum/n.
// S symmetric -> tiles bi <= bj (2080); off-diag tiles emit row AND col sums.
// r6 lessons: (1) ~14 us fixed cost per graph node -> fused 9 nodes into 5.
// (2) k_scl is staging-bound (global->LDS bytes), not MFMA-bound -> fp8
// halves staged bytes + LDS traffic; BK=128 halves barrier count.
// r4 lesson kept: never force waves/EU (spill tripwire: VGPR_Count collapse).

#define B_N 8192
#define D_K 768
#define NLAB 7
#define MBOUND 3.3333333333333335f /* 1/TEMP */
#define RTINV 1.8257418583505538f  /* 1/sqrt(TEMP) */

typedef float f32x4 __attribute__((ext_vector_type(4)));

__device__ __forceinline__ void gl2lds16(const void* g, void* l) {
  __builtin_amdgcn_global_load_lds(
      (const __attribute__((address_space(1))) void*)g,
      (__attribute__((address_space(3))) void*)l, 16, 0, 0);
}

// exact fp8 e4m3fn -> f32 decode (branch-free-ish; subnormal handled)
__device__ __forceinline__ float dec8(unsigned int b) {
  unsigned int s = (b >> 7) & 1u, e = (b >> 3) & 15u, m = b & 7u;
  float fn = __uint_as_float((s << 31) | ((e + 120u) << 23) | (m << 20));
  float fs = (s ? -1.f : 1.f) * (float)m * 0.001953125f;  // m * 2^-9
  return e ? fn : fs;
}

// ---- node 2: k_prep = normalize->fp8 quant + logits + per-row CE ----
__global__ __launch_bounds__(256) void k_prep(
    const float* __restrict__ cls, const float* __restrict__ pooled,
    const int* __restrict__ labels, const float* __restrict__ W,
    const float* __restrict__ bias, unsigned char* __restrict__ e8,
    float* __restrict__ logits_out, float* __restrict__ celoss) {
  int wv = threadIdx.x >> 6, lane = threadIdx.x & 63;
  int row = blockIdx.x * 4 + wv;

  // --- phase 1: normalize + quantize to fp8 ---
  const float4* src = (const float4*)(cls + (size_t)row * D_K);
  float4 x[3];
  float ss = 0.f;
#pragma unroll
  for (int j = 0; j < 3; ++j) {
    x[j] = src[j * 64 + lane];
    ss += x[j].x * x[j].x + x[j].y * x[j].y + x[j].z * x[j].z + x[j].w * x[j].w;
  }
#pragma unroll
  for (int m = 1; m < 64; m <<= 1) ss += __shfl_xor(ss, m);
  float sc = rsqrtf(ss) * RTINV;
  int* dst = (int*)(e8 + (size_t)row * D_K);
#pragma unroll
  for (int j = 0; j < 3; ++j) {
    int w32 = __builtin_amdgcn_cvt_pk_fp8_f32(x[j].x * sc, x[j].y * sc, 0, false);
    w32 = __builtin_amdgcn_cvt_pk_fp8_f32(x[j].z * sc, x[j].w * sc, w32, true);
    dst[j * 64 + lane] = w32;
  }

  // --- phase 2: logits + CE for the same row ---
  const float4* p4 = (const float4*)(pooled + (size_t)row * D_K);
  float acc[NLAB];
#pragma unroll
  for (int c = 0; c < NLAB; ++c) acc[c] = 0.f;
#pragma unroll
  for (int j = 0; j < 3; ++j) {
    float4 xx = p4[j * 64 + lane];
#pragma unroll
    for (int c = 0; c < NLAB; ++c) {
      float4 w = ((const float4*)(W + c * D_K))[j * 64 + lane];
      acc[c] += xx.x * w.x + xx.y * w.y + xx.z * w.z + xx.w * w.w;
    }
  }
#pragma unroll
  for (int c = 0; c < NLAB; ++c)
#pragma unroll
    for (int m = 1; m < 64; m <<= 1) acc[c] += __shfl_xor(acc[c], m);
  if (lane == 0) {
    float l[NLAB], mx = -1e30f;
#pragma unroll
    for (int c = 0; c < NLAB; ++c) { l[c] = acc[c] + bias[c]; mx = fmaxf(mx, l[c]); }
    float se = 0.f;
#pragma unroll
    for (int c = 0; c < NLAB; ++c) se += __expf(l[c] - mx);
    float lse = mx + __logf(se);
    celoss[row] = lse - l[labels[row]];
    float* o = logits_out + (size_t)row * NLAB;
#pragma unroll
    for (int c = 0; c < NLAB; ++c) o[c] = l[c];
  }
}

// ---- node 3: class sums (waves 0-2: 4 cols/thread, atomics into T) + hist (wave 3) ----
__global__ __launch_bounds__(256) void k_classumA(const unsigned char* __restrict__ e8,
                                                  const int* __restrict__ labels,
                                                  float* __restrict__ T,
                                                  int* __restrict__ hist) {
  int g = blockIdx.x, t = threadIdx.x;
  int r0 = g * 128;
  if (t < 192) {
    float acc[NLAB][4];
#pragma unroll
    for (int c = 0; c < NLAB; ++c)
#pragma unroll
      for (int k = 0; k < 4; ++k) acc[c][k] = 0.f;
    for (int r = 0; r < 128; r += 4) {
      int lab[4];
      uchar4 u[4];
#pragma unroll
      for (int q = 0; q < 4; ++q) {
        int row = r0 + r + q;
        lab[q] = labels[row];
        u[q] = *(const uchar4*)(e8 + (size_t)row * D_K + t * 4);
      }
#pragma unroll
      for (int q = 0; q < 4; ++q) {
        float x0 = dec8(u[q].x), x1 = dec8(u[q].y);
        float x2 = dec8(u[q].z), x3 = dec8(u[q].w);
#pragma unroll
        for (int c = 0; c < NLAB; ++c) {
          bool m = (lab[q] == c);
          acc[c][0] += m ? x0 : 0.f;
          acc[c][1] += m ? x1 : 0.f;
          acc[c][2] += m ? x2 : 0.f;
          acc[c][3] += m ? x3 : 0.f;
        }
      }
    }
#pragma unroll
    for (int c = 0; c < NLAB; ++c)
#pragma unroll
      for (int k = 0; k < 4; ++k) atomicAdd(&T[c * D_K + t * 4 + k], acc[c][k]);
  } else {
    int lane = t - 192;
    int cnt[NLAB];
#pragma unroll
    for (int c = 0; c < NLAB; ++c) cnt[c] = 0;
#pragma unroll
    for (int q = 0; q < 2; ++q) {
      int lab = labels[r0 + q * 64 + lane];
#pragma unroll
      for (int c = 0; c < NLAB; ++c) cnt[c] += (lab == c);
    }
#pragma unroll
    for (int c = 0; c < NLAB; ++c)
#pragma unroll
      for (int m = 1; m < 64; m <<= 1) cnt[c] += __shfl_xor(cnt[c], m);
    if (lane == 0)
#pragma unroll
      for (int c = 0; c < NLAB; ++c) atomicAdd(&hist[c], cnt[c]);
  }
}

// ---- node 4: exp-sum S-tiles via fp8 MFMA, BK=128, upper-triangular supertiles ----
// LDS: row r (128 B = 8 x 16B pairs), pair p stored at slot (p + (r>>1)) & 7.
// DMA stays wave-uniform base + lane*16 (swizzle on the GLOBAL source addr);
// ds_read_b64 fragments land 2 lanes/bank-pair = conflict-free.
__global__ __launch_bounds__(256) void k_scl(const unsigned char* __restrict__ e8,
                                             float* __restrict__ rse) {
  __shared__ __align__(16) unsigned char As[128 * 128];
  __shared__ __align__(16) unsigned char Bs[128 * 128];

  // supertile decode: 8x8-block supertiles over the triangle
  int rem = blockIdx.x;
  int BI = 0, BJ = 0;
  for (;;) {
    int sz = (BI == BJ) ? 36 : 64;
    if (rem < sz) break;
    rem -= sz;
    if (++BJ == 8) { ++BI; BJ = BI; }
  }
  int bi, bj;
  if (BI == BJ) {
    int r = 0, w = 8;
    while (rem >= w) { rem -= w; ++r; --w; }
    bi = BI * 8 + r;
    bj = BJ * 8 + r + rem;
  } else {
    bi = BI * 8 + (rem >> 3);
    bj = BJ * 8 + (rem & 7);
  }

  const int i0 = bi * 128, j0 = bj * 128;
  const int tid = threadIdx.x, wv = tid >> 6, lane = tid & 63;
  const int quad = lane >> 4, cix = lane & 15;
  const int rowTile = 64 * (wv >> 1), colTile = 64 * (wv & 1);

  f32x4 acc[4][4] = {};

  for (int kc = 0; kc < 6; ++kc) {
    __syncthreads();
#pragma unroll
    for (int it = 0; it < 4; ++it) {
      int s = it * 256 + tid;        // 16B slot in [0,1024)
      int r = s >> 3;                // row 0..127
      int p = ((s & 7) - (r >> 1)) & 7;  // inverse of pair-rotate swizzle
      int lbase = (it * 256 + wv * 64) * 16;  // wave-uniform LDS base
      gl2lds16(e8 + (size_t)(i0 + r) * D_K + kc * 128 + p * 16, (char*)As + lbase);
      gl2lds16(e8 + (size_t)(j0 + r) * D_K + kc * 128 + p * 16, (char*)Bs + lbase);
    }
    __syncthreads();
#pragma unroll
    for (int h = 0; h < 4; ++h) {
      const int c = quad + 4 * h;  // 8B chunk index 0..15
      long aF[4];
#pragma unroll
      for (int mt = 0; mt < 4; ++mt) {
        int r = rowTile + 16 * mt + cix;
        int f = ((c >> 1) + (r >> 1)) & 7;
        aF[mt] = *(const long*)(As + r * 128 + f * 16 + (c & 1) * 8);
      }
#pragma unroll
      for (int nt = 0; nt < 4; ++nt) {  // bF streamed: 1 live frag
        int r = colTile + 16 * nt + cix;
        int f = ((c >> 1) + (r >> 1)) & 7;
        long bF = *(const long*)(Bs + r * 128 + f * 16 + (c & 1) * 8);
#pragma unroll
        for (int mt = 0; mt < 4; ++mt)
          acc[mt][nt] = __builtin_amdgcn_mfma_f32_16x16x32_fp8_fp8(
              aF[mt], bF, acc[mt][nt], 0, 0, 0);
      }
    }
  }

  // ---- epilogue: exp-sums only (C/D layout: col=lane&15, row=quad*4+rg) ----
  if (bi != bj) {
    float ce_col[4] = {0.f, 0.f, 0.f, 0.f};
#pragma unroll
    for (int mt = 0; mt < 4; ++mt) {
      int rowbase = i0 + rowTile + 16 * mt + quad * 4;
      float rs_e[4] = {0.f, 0.f, 0.f, 0.f};
#pragma unroll
      for (int nt = 0; nt < 4; ++nt) {
#pragma unroll
        for (int rg = 0; rg < 4; ++rg) {
          float e = __expf(acc[mt][nt][rg] - MBOUND);
          rs_e[rg] += e;
          ce_col[nt] += e;
        }
      }
#pragma unroll
      for (int rg = 0; rg < 4; ++rg)
#pragma unroll
        for (int m = 1; m <= 8; m <<= 1) rs_e[rg] += __shfl_xor(rs_e[rg], m);
      if (cix == 0)
#pragma unroll
        for (int rg = 0; rg < 4; ++rg) atomicAdd(&rse[rowbase + rg], rs_e[rg]);
    }
#pragma unroll
    for (int nt = 0; nt < 4; ++nt) {
      ce_col[nt] += __shfl_xor(ce_col[nt], 16);
      ce_col[nt] += __shfl_xor(ce_col[nt], 32);
    }
    if (quad == 0)
#pragma unroll
      for (int nt = 0; nt < 4; ++nt)
        atomicAdd(&rse[j0 + colTile + 16 * nt + cix], ce_col[nt]);
  } else {
#pragma unroll
    for (int mt = 0; mt < 4; ++mt) {
      int rowbase = i0 + rowTile + 16 * mt + quad * 4;
      float rs_e[4] = {0.f, 0.f, 0.f, 0.f};
#pragma unroll
      for (int nt = 0; nt < 4; ++nt) {
        int gcol = j0 + colTile + 16 * nt + cix;
#pragma unroll
        for (int rg = 0; rg < 4; ++rg) {
          bool dg = (rowbase + rg) == gcol;
          rs_e[rg] += dg ? 0.f : __expf(acc[mt][nt][rg] - MBOUND);
        }
      }
#pragma unroll
      for (int rg = 0; rg < 4; ++rg)
#pragma unroll
        for (int m = 1; m <= 8; m <<= 1) rs_e[rg] += __shfl_xor(rs_e[rg], m);
      if (cix == 0)
#pragma unroll
        for (int rg = 0; rg < 4; ++rg) atomicAdd(&rse[rowbase + rg], rs_e[rg]);
    }
  }
}

// ---- node 5: per-row combine + last-block final reduce ----
__global__ __launch_bounds__(256) void k_rowfinal(
    const float* __restrict__ rse, const unsigned char* __restrict__ e8,
    const float* __restrict__ T, const int* __restrict__ labels,
    const int* __restrict__ hist, const float* __restrict__ celoss,
    float* __restrict__ contrP, int* __restrict__ done_count,
    float* __restrict__ out) {
  __shared__ float part[4];
  int wv = threadIdx.x >> 6, lane = threadIdx.x & 63;
  int row = blockIdx.x * 4 + wv;
  int l = labels[row];
  const uint* e4 = (const uint*)(e8 + (size_t)row * D_K);
  const float4* t4 = (const float4*)(T + (size_t)l * D_K);
  float pd = 0.f, sd = 0.f;
#pragma unroll
  for (int j = 0; j < 3; ++j) {
    uint u = e4[j * 64 + lane];
    float4 t = t4[j * 64 + lane];
    float a0 = dec8(u & 0xff), a1 = dec8((u >> 8) & 0xff);
    float a2 = dec8((u >> 16) & 0xff), a3 = dec8(u >> 24);
    pd += a0 * t.x + a1 * t.y + a2 * t.z + a3 * t.w;
    sd += a0 * a0 + a1 * a1 + a2 * a2 + a3 * a3;
  }
#pragma unroll
  for (int m = 1; m < 64; m <<= 1) {
    pd += __shfl_xor(pd, m);
    sd += __shfl_xor(sd, m);
  }
  if (lane == 0) {
    int ni = hist[l] - 1;
    float per = 0.f;
    if (ni > 0) {
      float possum = pd - sd;
      per = MBOUND + __logf(rse[row]) - possum / (float)ni;
    }
    part[wv] = 0.9f * per + (0.1f / (float)B_N) * celoss[row];
  }
  __syncthreads();
  if (threadIdx.x == 0) {
    float v = part[0] + part[1] + part[2] + part[3];
    atomicAdd(&contrP[(blockIdx.x & 63) * 16], v);
    __threadfence();
    int n = atomicAdd(done_count, 1);
    if (n == (int)gridDim.x - 1) {  // last block: device-scope reads of partials
      float s = 0.f;
      for (int i = 0; i < 64; ++i)
        s += __hip_atomic_load(&contrP[i * 16], __ATOMIC_RELAXED,
                               __HIP_MEMORY_SCOPE_AGENT);
      out[0] = s;
    }
  }
}

extern "C" void kernel_launch(void* const* d_in, const int* in_sizes, int n_in,
                              void* d_out, int out_size, void* d_ws, size_t ws_size,
                              hipStream_t stream) {
  const float* cls    = (const float*)d_in[0];
  const float* pooled = (const float*)d_in[1];
  const int*   labels = (const int*)d_in[2];
  const float* W      = (const float*)d_in[3];
  const float* bias   = (const float*)d_in[4];
  float* out = (float*)d_out;

  // workspace layout (~6.4 MB total; proven ws_size >= 12.65 MB)
  char* ws = (char*)d_ws;
  unsigned char* e8 = (unsigned char*)ws;              // 8192*768 = 6291456 B
  size_t off = (size_t)B_N * D_K;
  float* rse     = (float*)(ws + off);                 // +0      (32768 B)
  int*   hist    = (int*)(ws + off + 32768);           // +32768  (28 B, pad 128)
  int*   done    = (int*)(ws + off + 32896);           // +32896  (4 B, pad 128)
  float* contrP  = (float*)(ws + off + 33024);         // +33024  (4096 B)
  float* T       = (float*)(ws + off + 37120);         // +37120  (21504 B)
  float* celoss  = (float*)(ws + off + 58624);         // +58624  (32768 B, fully written)

  hipMemsetAsync(ws + off, 0, 58624, stream);  // zero rse/hist/done/contrP/T

  k_prep<<<B_N / 4, 256, 0, stream>>>(cls, pooled, labels, W, bias, e8, out + 1, celoss);
  k_classumA<<<64, 256, 0, stream>>>(e8, labels, T, hist);
  k_scl<<<2080, 256, 0, stream>>>(e8, rse);
  k_rowfinal<<<B_N / 4, 256, 0, stream>>>(rse, e8, T, labels, hist, celoss, contrP, done, out);
}

// Round 8
// 272.870 us; speedup vs baseline: 1.0643x; 1.0643x over previous
//
#include <hip/hip_runtime.h>
#include <hip/hip_bf16.h>

// BERT_SCL: loss = 0.9 * supcon(cls_emb, labels) + 0.1 * CE(pooled@W.T + b, labels)
// d_out[0] = loss, d_out[1..57344] = logits (8192 x 7, f32)
//
// en = bf16( row-normalized cls * 1/sqrt(TEMP) ).  S_ij = en_i . en_j <= M=1/TEMP
// -> fixed-max logsumexp. possum_i = en_i.T_{l_i} - ||en_i||^2 (positive mask is
// linear in S) -> big MFMA kernel computes ONLY exp-sums. Both lse and possum
// use the SAME quantized en -> quantization shift cancels to first order.
// S symmetric -> tiles bi <= bj (2080); off-diag tiles emit row AND col sums.
// Supertile swizzle (8x8) keeps the co-resident panel set inside per-XCD L2.
//
// Ledger of measured lessons:
//  r2: single-address f32 atomic x8192 ~ 100us -> per-row arrays / slot-spread.
//  r3: supertile swizzle fixes L2 thrash (FETCH 152->65MB).
//  r4: forcing waves/EU spills acc (VGPR 48 + 363MB scratch) -> never force.
//  r5: small-grid kernels (<1 blk/CU) are latency-bound -> two-stage reduce.
//  r6: ~14us per graph node -> fuse; k_scl is staging/latency-bound not MFMA.
//  r7: non-scaled fp8 MFMA = bf16 rate (no win); fp8 addressing cost VGPR
//      132 (-1 occupancy tier) + 6.4M LDS bank conflicts; software fp8 decode
//      too heavy for small kernels. -> reverted to the r6 bf16 k_scl.

#define B_N 8192
#define D_K 768
#define NLAB 7
#define MBOUND 3.3333333333333335f /* 1/TEMP */
#define RTINV 1.8257418583505538f  /* 1/sqrt(TEMP) */

typedef short s16x8 __attribute__((ext_vector_type(8)));
typedef float f32x4 __attribute__((ext_vector_type(4)));

__device__ __forceinline__ void gl2lds16(const void* g, void* l) {
  __builtin_amdgcn_global_load_lds(
      (const __attribute__((address_space(1))) void*)g,
      (__attribute__((address_space(3))) void*)l, 16, 0, 0);
}

__device__ __forceinline__ float bf16u_to_f(unsigned short u) {
  unsigned int w = ((unsigned int)u) << 16;
  return __uint_as_float(w);
}

// ---- node 1: k_prep = zero accumulators + normalize->bf16 + logits + CE ----
__global__ __launch_bounds__(256) void k_prep(
    const float* __restrict__ cls, const float* __restrict__ pooled,
    const int* __restrict__ labels, const float* __restrict__ W,
    const float* __restrict__ bias, unsigned short* __restrict__ en,
    float* __restrict__ logits_out, float* __restrict__ celoss,
    int* __restrict__ zr) {
  // block 0 zeros rse/hist/done/contrP (9280 ints); consumers run in later nodes
  if (blockIdx.x == 0)
    for (int t = threadIdx.x; t < 9280; t += 256) zr[t] = 0;

  int wv = threadIdx.x >> 6, lane = threadIdx.x & 63;
  int row = blockIdx.x * 4 + wv;

  // --- phase 1: normalize + quantize to bf16 ---
  const float4* src = (const float4*)(cls + (size_t)row * D_K);
  float4 x[3];
  float ss = 0.f;
#pragma unroll
  for (int j = 0; j < 3; ++j) {
    x[j] = src[j * 64 + lane];
    ss += x[j].x * x[j].x + x[j].y * x[j].y + x[j].z * x[j].z + x[j].w * x[j].w;
  }
#pragma unroll
  for (int m = 1; m < 64; m <<= 1) ss += __shfl_xor(ss, m);
  float sc = rsqrtf(ss) * RTINV;
  ushort4* dst = (ushort4*)(en + (size_t)row * D_K);
#pragma unroll
  for (int j = 0; j < 3; ++j) {
    const float* xv = reinterpret_cast<const float*>(&x[j]);
    ushort4 o;
    unsigned short* ov = reinterpret_cast<unsigned short*>(&o);
#pragma unroll
    for (int k = 0; k < 4; ++k) {
      __hip_bfloat16 h = __float2bfloat16(xv[k] * sc);
      ov[k] = *reinterpret_cast<unsigned short*>(&h);
    }
    dst[j * 64 + lane] = o;
  }

  // --- phase 2: logits + CE for the same row ---
  const float4* p4 = (const float4*)(pooled + (size_t)row * D_K);
  float acc[NLAB];
#pragma unroll
  for (int c = 0; c < NLAB; ++c) acc[c] = 0.f;
#pragma unroll
  for (int j = 0; j < 3; ++j) {
    float4 xx = p4[j * 64 + lane];
#pragma unroll
    for (int c = 0; c < NLAB; ++c) {
      float4 w = ((const float4*)(W + c * D_K))[j * 64 + lane];
      acc[c] += xx.x * w.x + xx.y * w.y + xx.z * w.z + xx.w * w.w;
    }
  }
#pragma unroll
  for (int c = 0; c < NLAB; ++c)
#pragma unroll
    for (int m = 1; m < 64; m <<= 1) acc[c] += __shfl_xor(acc[c], m);
  if (lane == 0) {
    float l[NLAB], mx = -1e30f;
#pragma unroll
    for (int c = 0; c < NLAB; ++c) { l[c] = acc[c] + bias[c]; mx = fmaxf(mx, l[c]); }
    float se = 0.f;
#pragma unroll
    for (int c = 0; c < NLAB; ++c) se += __expf(l[c] - mx);
    float lse = mx + __logf(se);
    celoss[row] = lse - l[labels[row]];
    float* o = logits_out + (size_t)row * NLAB;
#pragma unroll
    for (int c = 0; c < NLAB; ++c) o[c] = l[c];
  }
}

// ---- node 2: class-sum stage A (waves 0-2, direct stores) + hist (wave 3) ----
// block g sums rows [g*128, g*128+128) into partial[g][c][k]; thread t<192 owns
// cols [t*4, t*4+4).
__global__ __launch_bounds__(256) void k_classumA(const unsigned short* __restrict__ en,
                                                  const int* __restrict__ labels,
                                                  float* __restrict__ partial,
                                                  int* __restrict__ hist) {
  int g = blockIdx.x, t = threadIdx.x;
  int r0 = g * 128;
  if (t < 192) {
    float acc[NLAB][4];
#pragma unroll
    for (int c = 0; c < NLAB; ++c)
#pragma unroll
      for (int k = 0; k < 4; ++k) acc[c][k] = 0.f;
    for (int r = 0; r < 128; r += 4) {
      int lab[4];
      ushort4 u[4];
#pragma unroll
      for (int q = 0; q < 4; ++q) {
        int row = r0 + r + q;
        lab[q] = labels[row];
        u[q] = *(const ushort4*)(en + (size_t)row * D_K + t * 4);
      }
#pragma unroll
      for (int q = 0; q < 4; ++q) {
        float x0 = bf16u_to_f(u[q].x), x1 = bf16u_to_f(u[q].y);
        float x2 = bf16u_to_f(u[q].z), x3 = bf16u_to_f(u[q].w);
#pragma unroll
        for (int c = 0; c < NLAB; ++c) {
          bool m = (lab[q] == c);
          acc[c][0] += m ? x0 : 0.f;
          acc[c][1] += m ? x1 : 0.f;
          acc[c][2] += m ? x2 : 0.f;
          acc[c][3] += m ? x3 : 0.f;
        }
      }
    }
    float* dst = partial + (size_t)g * (NLAB * D_K);
#pragma unroll
    for (int c = 0; c < NLAB; ++c) {
      float4 v = {acc[c][0], acc[c][1], acc[c][2], acc[c][3]};
      *(float4*)(dst + c * D_K + t * 4) = v;
    }
  } else {
    int lane = t - 192;
    int cnt[NLAB];
#pragma unroll
    for (int c = 0; c < NLAB; ++c) cnt[c] = 0;
#pragma unroll
    for (int q = 0; q < 2; ++q) {
      int lab = labels[r0 + q * 64 + lane];
#pragma unroll
      for (int c = 0; c < NLAB; ++c) cnt[c] += (lab == c);
    }
#pragma unroll
    for (int c = 0; c < NLAB; ++c)
#pragma unroll
      for (int m = 1; m < 64; m <<= 1) cnt[c] += __shfl_xor(cnt[c], m);
    if (lane == 0)
#pragma unroll
      for (int c = 0; c < NLAB; ++c) atomicAdd(&hist[c], cnt[c]);
  }
}

// ---- node 3: class-sum stage B: T[idx] = sum_g partial[g][idx] ----
__global__ __launch_bounds__(256) void k_classumB(const float* __restrict__ partial,
                                                  float* __restrict__ T) {
  int idx = blockIdx.x * 256 + threadIdx.x;  // 21 blocks -> 5376
  float v = 0.f;
  for (int g = 0; g < 64; ++g) v += partial[(size_t)g * (NLAB * D_K) + idx];
  T[idx] = v;
}

// ---- node 4: exp-sum S-tiles via bf16 MFMA, upper-triangular supertiles ----
// (r6-proven: VGPR 112, 0 bank conflicts, ~104 us)
__global__ __launch_bounds__(256) void k_scl(const unsigned short* __restrict__ en,
                                             float* __restrict__ rse) {
  __shared__ __align__(16) unsigned short As[128 * 64];
  __shared__ __align__(16) unsigned short Bs[128 * 64];

  int rem = blockIdx.x;
  int BI = 0, BJ = 0;
  for (;;) {
    int sz = (BI == BJ) ? 36 : 64;
    if (rem < sz) break;
    rem -= sz;
    if (++BJ == 8) { ++BI; BJ = BI; }
  }
  int bi, bj;
  if (BI == BJ) {
    int r = 0, w = 8;
    while (rem >= w) { rem -= w; ++r; --w; }
    bi = BI * 8 + r;
    bj = BJ * 8 + r + rem;
  } else {
    bi = BI * 8 + (rem >> 3);
    bj = BJ * 8 + (rem & 7);
  }

  const int i0 = bi * 128, j0 = bj * 128;
  const int tid = threadIdx.x, wv = tid >> 6, lane = tid & 63;
  const int quad = lane >> 4, cix = lane & 15;
  const int rowTile = 64 * (wv >> 1), colTile = 64 * (wv & 1);

  f32x4 acc[4][4] = {};

  for (int kc = 0; kc < 12; ++kc) {
    __syncthreads();
#pragma unroll
    for (int it = 0; it < 4; ++it) {
      int s = it * 256 + tid;
      int r = s >> 3;
      int c = ((s & 7) - r) & 7;  // inverse of write swizzle
      int lbase = (it * 256 + wv * 64) * 16;  // wave-uniform LDS base (bytes)
      gl2lds16(en + (size_t)(i0 + r) * D_K + kc * 64 + c * 8, (char*)As + lbase);
      gl2lds16(en + (size_t)(j0 + r) * D_K + kc * 64 + c * 8, (char*)Bs + lbase);
    }
    __syncthreads();
#pragma unroll
    for (int h = 0; h < 2; ++h) {
      const int cc = quad + 4 * h;
      s16x8 aF[4];
#pragma unroll
      for (int mt = 0; mt < 4; ++mt) {
        int r = rowTile + 16 * mt + cix;
        aF[mt] = *reinterpret_cast<const s16x8*>((const char*)As +
                                                 (r * 8 + ((cc + r) & 7)) * 16);
      }
#pragma unroll
      for (int nt = 0; nt < 4; ++nt) {  // bF streamed: 1 live frag
        int r = colTile + 16 * nt + cix;
        s16x8 bF = *reinterpret_cast<const s16x8*>((const char*)Bs +
                                                   (r * 8 + ((cc + r) & 7)) * 16);
#pragma unroll
        for (int mt = 0; mt < 4; ++mt)
          acc[mt][nt] = __builtin_amdgcn_mfma_f32_16x16x32_bf16(
              aF[mt], bF, acc[mt][nt], 0, 0, 0);
      }
    }
  }

  // ---- epilogue: exp-sums only (C/D: col=lane&15, row=quad*4+rg) ----
  if (bi != bj) {
    float ce_col[4] = {0.f, 0.f, 0.f, 0.f};
#pragma unroll
    for (int mt = 0; mt < 4; ++mt) {
      int rowbase = i0 + rowTile + 16 * mt + quad * 4;
      float rs_e[4] = {0.f, 0.f, 0.f, 0.f};
#pragma unroll
      for (int nt = 0; nt < 4; ++nt) {
#pragma unroll
        for (int rg = 0; rg < 4; ++rg) {
          float e = __expf(acc[mt][nt][rg] - MBOUND);
          rs_e[rg] += e;
          ce_col[nt] += e;
        }
      }
#pragma unroll
      for (int rg = 0; rg < 4; ++rg)
#pragma unroll
        for (int m = 1; m <= 8; m <<= 1) rs_e[rg] += __shfl_xor(rs_e[rg], m);
      if (cix == 0)
#pragma unroll
        for (int rg = 0; rg < 4; ++rg) atomicAdd(&rse[rowbase + rg], rs_e[rg]);
    }
#pragma unroll
    for (int nt = 0; nt < 4; ++nt) {
      ce_col[nt] += __shfl_xor(ce_col[nt], 16);
      ce_col[nt] += __shfl_xor(ce_col[nt], 32);
    }
    if (quad == 0)
#pragma unroll
      for (int nt = 0; nt < 4; ++nt)
        atomicAdd(&rse[j0 + colTile + 16 * nt + cix], ce_col[nt]);
  } else {
#pragma unroll
    for (int mt = 0; mt < 4; ++mt) {
      int rowbase = i0 + rowTile + 16 * mt + quad * 4;
      float rs_e[4] = {0.f, 0.f, 0.f, 0.f};
#pragma unroll
      for (int nt = 0; nt < 4; ++nt) {
        int gcol = j0 + colTile + 16 * nt + cix;
#pragma unroll
        for (int rg = 0; rg < 4; ++rg) {
          bool dg = (rowbase + rg) == gcol;
          rs_e[rg] += dg ? 0.f : __expf(acc[mt][nt][rg] - MBOUND);
        }
      }
#pragma unroll
      for (int rg = 0; rg < 4; ++rg)
#pragma unroll
        for (int m = 1; m <= 8; m <<= 1) rs_e[rg] += __shfl_xor(rs_e[rg], m);
      if (cix == 0)
#pragma unroll
        for (int rg = 0; rg < 4; ++rg) atomicAdd(&rse[rowbase + rg], rs_e[rg]);
    }
  }
}

// ---- node 5: per-row combine + last-block final reduce ----
__global__ __launch_bounds__(256) void k_rowfinal(
    const float* __restrict__ rse, const unsigned short* __restrict__ en,
    const float* __restrict__ T, const int* __restrict__ labels,
    const int* __restrict__ hist, const float* __restrict__ celoss,
    float* __restrict__ contrP, int* __restrict__ done_count,
    float* __restrict__ out) {
  __shared__ float part[4];
  int wv = threadIdx.x >> 6, lane = threadIdx.x & 63;
  int row = blockIdx.x * 4 + wv;
  int l = labels[row];
  const ushort4* e4 = (const ushort4*)(en + (size_t)row * D_K);
  const float4* t4 = (const float4*)(T + (size_t)l * D_K);
  float pd = 0.f, sd = 0.f;
#pragma unroll
  for (int j = 0; j < 3; ++j) {
    ushort4 u = e4[j * 64 + lane];
    float4 t = t4[j * 64 + lane];
    float a0 = bf16u_to_f(u.x), a1 = bf16u_to_f(u.y);
    float a2 = bf16u_to_f(u.z), a3 = bf16u_to_f(u.w);
    pd += a0 * t.x + a1 * t.y + a2 * t.z + a3 * t.w;
    sd += a0 * a0 + a1 * a1 + a2 * a2 + a3 * a3;
  }
#pragma unroll
  for (int m = 1; m < 64; m <<= 1) {
    pd += __shfl_xor(pd, m);
    sd += __shfl_xor(sd, m);
  }
  if (lane == 0) {
    int ni = hist[l] - 1;
    float per = 0.f;
    if (ni > 0) {
      float possum = pd - sd;
      per = MBOUND + __logf(rse[row]) - possum / (float)ni;
    }
    part[wv] = 0.9f * per + (0.1f / (float)B_N) * celoss[row];
  }
  __syncthreads();
  if (threadIdx.x == 0) {
    float v = part[0] + part[1] + part[2] + part[3];
    atomicAdd(&contrP[(blockIdx.x & 63) * 16], v);
    __threadfence();
    int n = atomicAdd(done_count, 1);
    if (n == (int)gridDim.x - 1) {  // last block: device-scope reads of partials
      float s = 0.f;
      for (int i = 0; i < 64; ++i)
        s += __hip_atomic_load(&contrP[i * 16], __ATOMIC_RELAXED,
                               __HIP_MEMORY_SCOPE_AGENT);
      out[0] = s;
    }
  }
}

extern "C" void kernel_launch(void* const* d_in, const int* in_sizes, int n_in,
                              void* d_out, int out_size, void* d_ws, size_t ws_size,
                              hipStream_t stream) {
  const float* cls    = (const float*)d_in[0];
  const float* pooled = (const float*)d_in[1];
  const int*   labels = (const int*)d_in[2];
  const float* W      = (const float*)d_in[3];
  const float* bias   = (const float*)d_in[4];
  float* out = (float*)d_out;

  // workspace layout (total 14057472 B — exactly what r6 proved available)
  char* ws = (char*)d_ws;
  unsigned short* en = (unsigned short*)ws;            // 12582912 B
  size_t off = (size_t)B_N * D_K * 2;
  float* rse     = (float*)(ws + off);                 // +0      (32768 B) [zeroed]
  int*   hist    = (int*)(ws + off + 32768);           // +32768  (128 B)   [zeroed]
  int*   done    = (int*)(ws + off + 32896);           // +32896  (128 B)   [zeroed]
  float* contrP  = (float*)(ws + off + 33024);         // +33024  (4096 B)  [zeroed]
  float* T       = (float*)(ws + off + 37120);         // +37120  (21504 B, fully written)
  float* celoss  = (float*)(ws + off + 58624);         // +58624  (32768 B, fully written)
  float* partial = (float*)(ws + off + 98304);         // +98304  (1376256 B, fully written)
  int*   zr      = (int*)(ws + off);                   // 9280 ints = rse..contrP

  k_prep<<<B_N / 4, 256, 0, stream>>>(cls, pooled, labels, W, bias, en, out + 1,
                                      celoss, zr);
  k_classumA<<<64, 256, 0, stream>>>(en, labels, partial, hist);
  k_classumB<<<21, 256, 0, stream>>>(partial, T);
  k_scl<<<2080, 256, 0, stream>>>(en, rse);
  k_rowfinal<<<B_N / 4, 256, 0, stream>>>(rse, en, T, labels, hist, celoss, contrP,
                                          done, out);
}

// Round 9
// 225.529 us; speedup vs baseline: 1.2877x; 1.2099x over previous
//
#include <hip/hip_runtime.h>
#include <hip/hip_bf16.h>

// BERT_SCL: loss = 0.9 * supcon(cls_emb, labels) + 0.1 * CE(pooled@W.T + b, labels)
// d_out[0] = loss, d_out[1..57344] = logits (8192 x 7, f32)
//
// e8 = fp8_e4m3(row-normalized cls * 1/sqrt(TEMP)); en = bf16 of the same.
// S_ij = e8_i . e8_j <= M = 1/TEMP -> fixed-max logsumexp. possum_i =
// en_i.T_{l_i} - ||en_i||^2 (positive mask linear in S) -> big kernel does
// ONLY exp-sums, via MX-scaled fp8 MFMA (16x16x128, unit scales 0x7F) = the
// only low-precision fast path on CDNA4 (2x bf16 rate, K=128/inst).
// S symmetric -> tiles bi <= bj (2080); off-diag tiles emit row AND col sums.
// Supertile swizzle (8x8) keeps co-resident panels in per-XCD L2.
//
// Ledger: r2 single-address atomics ~100us; r3 supertile fixes L2 thrash;
// r4 forced waves/EU -> acc spill (VGPR 48, 363MB scratch) = never force;
// r5 <1blk/CU kernels latency-bound; r6 k_scl staging/latency-bound;
// r7 non-scaled fp8 = bf16 rate + half-row swizzle broke banking (6.4M
// conflicts) + dec8 too heavy for small kernels -> fixed here: SCALED MFMA,
// full-row rotate swizzle (same bank distribution as the 0-conflict bf16
// kernel), dual-format e8+bf16 so small kernels keep their proven bf16 paths.
// r8: node count is a weak lever (~120us residual is launch/drain overhead).

#define B_N 8192
#define D_K 768
#define NLAB 7
#define MBOUND 3.3333333333333335f /* 1/TEMP */
#define RTINV 1.8257418583505538f  /* 1/sqrt(TEMP) */

typedef float f32x4 __attribute__((ext_vector_type(4)));
typedef int i32x8 __attribute__((ext_vector_type(8)));

__device__ __forceinline__ void gl2lds16(const void* g, void* l) {
  __builtin_amdgcn_global_load_lds(
      (const __attribute__((address_space(1))) void*)g,
      (__attribute__((address_space(3))) void*)l, 16, 0, 0);
}

__device__ __forceinline__ float bf16u_to_f(unsigned short u) {
  return __uint_as_float(((unsigned int)u) << 16);
}

// exact fp8 e4m3fn -> f32 decode (fallback paths only)
__device__ __forceinline__ float dec8(unsigned int b) {
  unsigned int s = (b >> 7) & 1u, e = (b >> 3) & 15u, m = b & 7u;
  float fn = __uint_as_float((s << 31) | ((e + 120u) << 23) | (m << 20));
  float fs = (s ? -1.f : 1.f) * (float)m * 0.001953125f;
  return e ? fn : fs;
}

// ---- node 1: k_prep = zero accumulators + normalize -> {fp8, bf16} + logits + CE ----
template <int WBF>
__global__ __launch_bounds__(256) void k_prep(
    const float* __restrict__ cls, const float* __restrict__ pooled,
    const int* __restrict__ labels, const float* __restrict__ W,
    const float* __restrict__ bias, unsigned char* __restrict__ e8,
    unsigned short* __restrict__ en, float* __restrict__ logits_out,
    float* __restrict__ celoss, int* __restrict__ zr) {
  if (blockIdx.x == 0)
    for (int t = threadIdx.x; t < 9280; t += 256) zr[t] = 0;

  int wv = threadIdx.x >> 6, lane = threadIdx.x & 63;
  int row = blockIdx.x * 4 + wv;

  // --- normalize + quantize ---
  const float4* src = (const float4*)(cls + (size_t)row * D_K);
  float4 x[3];
  float ss = 0.f;
#pragma unroll
  for (int j = 0; j < 3; ++j) {
    x[j] = src[j * 64 + lane];
    ss += x[j].x * x[j].x + x[j].y * x[j].y + x[j].z * x[j].z + x[j].w * x[j].w;
  }
#pragma unroll
  for (int m = 1; m < 64; m <<= 1) ss += __shfl_xor(ss, m);
  float sc = rsqrtf(ss) * RTINV;
  int* d8 = (int*)(e8 + (size_t)row * D_K);
  ushort4* db = (ushort4*)(en + (size_t)row * D_K);
#pragma unroll
  for (int j = 0; j < 3; ++j) {
    int w32 = __builtin_amdgcn_cvt_pk_fp8_f32(x[j].x * sc, x[j].y * sc, 0, false);
    w32 = __builtin_amdgcn_cvt_pk_fp8_f32(x[j].z * sc, x[j].w * sc, w32, true);
    d8[j * 64 + lane] = w32;
    if (WBF) {
      const float* xv = reinterpret_cast<const float*>(&x[j]);
      ushort4 o;
      unsigned short* ov = reinterpret_cast<unsigned short*>(&o);
#pragma unroll
      for (int k = 0; k < 4; ++k) {
        __hip_bfloat16 h = __float2bfloat16(xv[k] * sc);
        ov[k] = *reinterpret_cast<unsigned short*>(&h);
      }
      db[j * 64 + lane] = o;
    }
  }

  // --- logits + CE ---
  const float4* p4 = (const float4*)(pooled + (size_t)row * D_K);
  float acc[NLAB];
#pragma unroll
  for (int c = 0; c < NLAB; ++c) acc[c] = 0.f;
#pragma unroll
  for (int j = 0; j < 3; ++j) {
    float4 xx = p4[j * 64 + lane];
#pragma unroll
    for (int c = 0; c < NLAB; ++c) {
      float4 w = ((const float4*)(W + c * D_K))[j * 64 + lane];
      acc[c] += xx.x * w.x + xx.y * w.y + xx.z * w.z + xx.w * w.w;
    }
  }
#pragma unroll
  for (int c = 0; c < NLAB; ++c)
#pragma unroll
    for (int m = 1; m < 64; m <<= 1) acc[c] += __shfl_xor(acc[c], m);
  if (lane == 0) {
    float l[NLAB], mx = -1e30f;
#pragma unroll
    for (int c = 0; c < NLAB; ++c) { l[c] = acc[c] + bias[c]; mx = fmaxf(mx, l[c]); }
    float se = 0.f;
#pragma unroll
    for (int c = 0; c < NLAB; ++c) se += __expf(l[c] - mx);
    float lse = mx + __logf(se);
    celoss[row] = lse - l[labels[row]];
    float* o = logits_out + (size_t)row * NLAB;
#pragma unroll
    for (int c = 0; c < NLAB; ++c) o[c] = l[c];
  }
}

// ---- node 2: class-sum stage A (direct stores) + hist (wave 3) ----
// M=0: read bf16 en; M=1: read fp8 e8 (fallback).
template <int M>
__global__ __launch_bounds__(256) void k_classumA(
    const unsigned short* __restrict__ en, const unsigned char* __restrict__ e8,
    const int* __restrict__ labels, float* __restrict__ partial,
    int* __restrict__ hist) {
  int g = blockIdx.x, t = threadIdx.x;
  int r0 = g * 128;
  if (t < 192) {
    float acc[NLAB][4];
#pragma unroll
    for (int c = 0; c < NLAB; ++c)
#pragma unroll
      for (int k = 0; k < 4; ++k) acc[c][k] = 0.f;
    for (int r = 0; r < 128; r += 4) {
      int lab[4];
      float xv[4][4];
#pragma unroll
      for (int q = 0; q < 4; ++q) {
        int row = r0 + r + q;
        lab[q] = labels[row];
        if (M == 0) {
          ushort4 u = *(const ushort4*)(en + (size_t)row * D_K + t * 4);
          xv[q][0] = bf16u_to_f(u.x); xv[q][1] = bf16u_to_f(u.y);
          xv[q][2] = bf16u_to_f(u.z); xv[q][3] = bf16u_to_f(u.w);
        } else {
          uchar4 u = *(const uchar4*)(e8 + (size_t)row * D_K + t * 4);
          xv[q][0] = dec8(u.x); xv[q][1] = dec8(u.y);
          xv[q][2] = dec8(u.z); xv[q][3] = dec8(u.w);
        }
      }
#pragma unroll
      for (int q = 0; q < 4; ++q)
#pragma unroll
        for (int c = 0; c < NLAB; ++c) {
          bool m = (lab[q] == c);
          acc[c][0] += m ? xv[q][0] : 0.f;
          acc[c][1] += m ? xv[q][1] : 0.f;
          acc[c][2] += m ? xv[q][2] : 0.f;
          acc[c][3] += m ? xv[q][3] : 0.f;
        }
    }
    float* dst = partial + (size_t)g * (NLAB * D_K);
#pragma unroll
    for (int c = 0; c < NLAB; ++c) {
      float4 v = {acc[c][0], acc[c][1], acc[c][2], acc[c][3]};
      *(float4*)(dst + c * D_K + t * 4) = v;
    }
  } else {
    int lane = t - 192;
    int cnt[NLAB];
#pragma unroll
    for (int c = 0; c < NLAB; ++c) cnt[c] = 0;
#pragma unroll
    for (int q = 0; q < 2; ++q) {
      int lab = labels[r0 + q * 64 + lane];
#pragma unroll
      for (int c = 0; c < NLAB; ++c) cnt[c] += (lab == c);
    }
#pragma unroll
    for (int c = 0; c < NLAB; ++c)
#pragma unroll
      for (int m = 1; m < 64; m <<= 1) cnt[c] += __shfl_xor(cnt[c], m);
    if (lane == 0)
#pragma unroll
      for (int c = 0; c < NLAB; ++c) atomicAdd(&hist[c], cnt[c]);
  }
}

// ---- node 3: exp-sum S-tiles via MX-scaled fp8 MFMA (16x16x128), upper-tri ----
// Blocks >= 2080 run class-sum stage B (only needs node-2 output).
// LDS: row r = 128 B = 8 chunks of 16 B; chunk c stored at slot (c + r) & 7.
// DMA dest stays wave-uniform base + lane*16 (swizzle on GLOBAL source addr).
// Fragment = 32 B/lane (k = quad*32 + j): two b128 reads, bank-group
// (quad*2 + cix) & 7 -> 8 lanes/group across the wave = same distribution as
// the measured-0-conflict bf16 kernel.
__global__ __launch_bounds__(256) void k_scl(const unsigned char* __restrict__ e8,
                                             float* __restrict__ rse,
                                             const float* __restrict__ partial,
                                             float* __restrict__ T) {
  if (blockIdx.x >= 2080) {  // classumB role: T[idx] = sum_g partial[g][idx]
    int idx = (int)(blockIdx.x - 2080) * 256 + threadIdx.x;  // < 5376
    float v = 0.f;
    for (int g = 0; g < 64; ++g) v += partial[(size_t)g * (NLAB * D_K) + idx];
    T[idx] = v;
    return;
  }
  __shared__ __align__(16) unsigned char As[128 * 128];
  __shared__ __align__(16) unsigned char Bs[128 * 128];

  // supertile decode: 8x8-block supertiles over the triangle
  int rem = blockIdx.x;
  int BI = 0, BJ = 0;
  for (;;) {
    int sz = (BI == BJ) ? 36 : 64;
    if (rem < sz) break;
    rem -= sz;
    if (++BJ == 8) { ++BI; BJ = BI; }
  }
  int bi, bj;
  if (BI == BJ) {
    int r = 0, w = 8;
    while (rem >= w) { rem -= w; ++r; --w; }
    bi = BI * 8 + r;
    bj = BJ * 8 + r + rem;
  } else {
    bi = BI * 8 + (rem >> 3);
    bj = BJ * 8 + (rem & 7);
  }

  const int i0 = bi * 128, j0 = bj * 128;
  const int tid = threadIdx.x, wv = tid >> 6, lane = tid & 63;
  const int quad = lane >> 4, cix = lane & 15;
  const int rowTile = 64 * (wv >> 1), colTile = 64 * (wv & 1);

  f32x4 acc[4][4] = {};

  for (int kc = 0; kc < 6; ++kc) {
    __syncthreads();
#pragma unroll
    for (int it = 0; it < 4; ++it) {
      int s = it * 256 + tid;            // 16B slot in [0,1024)
      int r = s >> 3;                    // row 0..127
      int p = ((s & 7) - r) & 7;         // inverse of write swizzle
      int lbase = (it * 256 + wv * 64) * 16;
      gl2lds16(e8 + (size_t)(i0 + r) * D_K + kc * 128 + p * 16, (char*)As + lbase);
      gl2lds16(e8 + (size_t)(j0 + r) * D_K + kc * 128 + p * 16, (char*)Bs + lbase);
    }
    __syncthreads();
    i32x8 aF[4];
#pragma unroll
    for (int mt = 0; mt < 4; ++mt) {
      int r = rowTile + 16 * mt + cix;
      const char* base = (const char*)As + r * 128;
      int4 lo = *(const int4*)(base + (((quad * 2 + 0) + r) & 7) * 16);
      int4 hi = *(const int4*)(base + (((quad * 2 + 1) + r) & 7) * 16);
      aF[mt][0] = lo.x; aF[mt][1] = lo.y; aF[mt][2] = lo.z; aF[mt][3] = lo.w;
      aF[mt][4] = hi.x; aF[mt][5] = hi.y; aF[mt][6] = hi.z; aF[mt][7] = hi.w;
    }
#pragma unroll
    for (int nt = 0; nt < 4; ++nt) {  // bF streamed: 1 live frag
      int r = colTile + 16 * nt + cix;
      const char* base = (const char*)Bs + r * 128;
      int4 lo = *(const int4*)(base + (((quad * 2 + 0) + r) & 7) * 16);
      int4 hi = *(const int4*)(base + (((quad * 2 + 1) + r) & 7) * 16);
      i32x8 bF;
      bF[0] = lo.x; bF[1] = lo.y; bF[2] = lo.z; bF[3] = lo.w;
      bF[4] = hi.x; bF[5] = hi.y; bF[6] = hi.z; bF[7] = hi.w;
#pragma unroll
      for (int mt = 0; mt < 4; ++mt)
        acc[mt][nt] = __builtin_amdgcn_mfma_scale_f32_16x16x128_f8f6f4(
            aF[mt], bF, acc[mt][nt], 0, 0, 0, 127, 0, 127);  // fp8 fmt, scale=1.0
    }
  }

  // ---- epilogue: exp-sums only (16x16 C/D: col=lane&15, row=quad*4+rg) ----
  if (bi != bj) {
    float ce_col[4] = {0.f, 0.f, 0.f, 0.f};
#pragma unroll
    for (int mt = 0; mt < 4; ++mt) {
      int rowbase = i0 + rowTile + 16 * mt + quad * 4;
      float rs_e[4] = {0.f, 0.f, 0.f, 0.f};
#pragma unroll
      for (int nt = 0; nt < 4; ++nt) {
#pragma unroll
        for (int rg = 0; rg < 4; ++rg) {
          float e = __expf(acc[mt][nt][rg] - MBOUND);
          rs_e[rg] += e;
          ce_col[nt] += e;
        }
      }
#pragma unroll
      for (int rg = 0; rg < 4; ++rg)
#pragma unroll
        for (int m = 1; m <= 8; m <<= 1) rs_e[rg] += __shfl_xor(rs_e[rg], m);
      if (cix == 0)
#pragma unroll
        for (int rg = 0; rg < 4; ++rg) atomicAdd(&rse[rowbase + rg], rs_e[rg]);
    }
#pragma unroll
    for (int nt = 0; nt < 4; ++nt) {
      ce_col[nt] += __shfl_xor(ce_col[nt], 16);
      ce_col[nt] += __shfl_xor(ce_col[nt], 32);
    }
    if (quad == 0)
#pragma unroll
      for (int nt = 0; nt < 4; ++nt)
        atomicAdd(&rse[j0 + colTile + 16 * nt + cix], ce_col[nt]);
  } else {
#pragma unroll
    for (int mt = 0; mt < 4; ++mt) {
      int rowbase = i0 + rowTile + 16 * mt + quad * 4;
      float rs_e[4] = {0.f, 0.f, 0.f, 0.f};
#pragma unroll
      for (int nt = 0; nt < 4; ++nt) {
        int gcol = j0 + colTile + 16 * nt + cix;
#pragma unroll
        for (int rg = 0; rg < 4; ++rg) {
          bool dg = (rowbase + rg) == gcol;
          rs_e[rg] += dg ? 0.f : __expf(acc[mt][nt][rg] - MBOUND);
        }
      }
#pragma unroll
      for (int rg = 0; rg < 4; ++rg)
#pragma unroll
        for (int m = 1; m <= 8; m <<= 1) rs_e[rg] += __shfl_xor(rs_e[rg], m);
      if (cix == 0)
#pragma unroll
        for (int rg = 0; rg < 4; ++rg) atomicAdd(&rse[rowbase + rg], rs_e[rg]);
    }
  }
}

// ---- node 4: per-row combine + last-block final reduce ----
template <int M>
__global__ __launch_bounds__(256) void k_rowfinal(
    const float* __restrict__ rse, const unsigned short* __restrict__ en,
    const unsigned char* __restrict__ e8, const float* __restrict__ T,
    const int* __restrict__ labels, const int* __restrict__ hist,
    const float* __restrict__ celoss, float* __restrict__ contrP,
    int* __restrict__ done_count, float* __restrict__ out) {
  __shared__ float part[4];
  int wv = threadIdx.x >> 6, lane = threadIdx.x & 63;
  int row = blockIdx.x * 4 + wv;
  int l = labels[row];
  const float4* t4 = (const float4*)(T + (size_t)l * D_K);
  float pd = 0.f, sd = 0.f;
#pragma unroll
  for (int j = 0; j < 3; ++j) {
    float a0, a1, a2, a3;
    if (M == 0) {
      ushort4 u = ((const ushort4*)(en + (size_t)row * D_K))[j * 64 + lane];
      a0 = bf16u_to_f(u.x); a1 = bf16u_to_f(u.y);
      a2 = bf16u_to_f(u.z); a3 = bf16u_to_f(u.w);
    } else {
      uint u = ((const uint*)(e8 + (size_t)row * D_K))[j * 64 + lane];
      a0 = dec8(u & 0xff); a1 = dec8((u >> 8) & 0xff);
      a2 = dec8((u >> 16) & 0xff); a3 = dec8(u >> 24);
    }
    float4 t = t4[j * 64 + lane];
    pd += a0 * t.x + a1 * t.y + a2 * t.z + a3 * t.w;
    sd += a0 * a0 + a1 * a1 + a2 * a2 + a3 * a3;
  }
#pragma unroll
  for (int m = 1; m < 64; m <<= 1) {
    pd += __shfl_xor(pd, m);
    sd += __shfl_xor(sd, m);
  }
  if (lane == 0) {
    int ni = hist[l] - 1;
    float per = 0.f;
    if (ni > 0) per = MBOUND + __logf(rse[row]) - (pd - sd) / (float)ni;
    part[wv] = 0.9f * per + (0.1f / (float)B_N) * celoss[row];
  }
  __syncthreads();
  if (threadIdx.x == 0) {
    float v = part[0] + part[1] + part[2] + part[3];
    atomicAdd(&contrP[(blockIdx.x & 63) * 16], v);
    __threadfence();
    int n = atomicAdd(done_count, 1);
    if (n == (int)gridDim.x - 1) {
      float s = 0.f;
      for (int i = 0; i < 64; ++i)
        s += __hip_atomic_load(&contrP[i * 16], __ATOMIC_RELAXED,
                               __HIP_MEMORY_SCOPE_AGENT);
      out[0] = s;
    }
  }
}

extern "C" void kernel_launch(void* const* d_in, const int* in_sizes, int n_in,
                              void* d_out, int out_size, void* d_ws, size_t ws_size,
                              hipStream_t stream) {
  const float* cls    = (const float*)d_in[0];
  const float* pooled = (const float*)d_in[1];
  const int*   labels = (const int*)d_in[2];
  const float* W      = (const float*)d_in[3];
  const float* bias   = (const float*)d_in[4];
  float* out = (float*)d_out;

  char* ws = (char*)d_ws;
  unsigned char* e8 = (unsigned char*)ws;          // 6291456 B
  // big layout: bf16 en after e8; fallback: tail right after e8 (14.06MB proven)
  const size_t EN_B = (size_t)B_N * D_K * 2;       // 12582912
  const size_t E8_B = (size_t)B_N * D_K;           // 6291456
  size_t need_big = E8_B + EN_B + 98304 + 64 * (size_t)(NLAB * D_K) * 4;
  bool big = ws_size >= need_big;                  // 20348928 B
  unsigned short* en = (unsigned short*)(ws + E8_B);
  size_t off = big ? (E8_B + EN_B) : E8_B;
  float* rse     = (float*)(ws + off);             // +0      (32768) [zeroed]
  int*   hist    = (int*)(ws + off + 32768);       // +32768  (128)   [zeroed]
  int*   done    = (int*)(ws + off + 32896);       // +32896  (128)   [zeroed]
  float* contrP  = (float*)(ws + off + 33024);     // +33024  (4096)  [zeroed]
  float* T       = (float*)(ws + off + 37120);     // +37120  (21504, fully written)
  float* celoss  = (float*)(ws + off + 58624);     // +58624  (32768, fully written)
  float* partial = (float*)(ws + off + 98304);     // +98304  (1376256, fully written)
  int*   zr      = (int*)(ws + off);               // 9280 ints = rse..contrP

  if (big)
    k_prep<1><<<B_N / 4, 256, 0, stream>>>(cls, pooled, labels, W, bias, e8, en,
                                           out + 1, celoss, zr);
  else
    k_prep<0><<<B_N / 4, 256, 0, stream>>>(cls, pooled, labels, W, bias, e8, en,
                                           out + 1, celoss, zr);
  if (big)
    k_classumA<0><<<64, 256, 0, stream>>>(en, e8, labels, partial, hist);
  else
    k_classumA<1><<<64, 256, 0, stream>>>(en, e8, labels, partial, hist);
  k_scl<<<2101, 256, 0, stream>>>(e8, rse, partial, T);  // +21 classumB blocks
  if (big)
    k_rowfinal<0><<<B_N / 4, 256, 0, stream>>>(rse, en, e8, T, labels, hist,
                                               celoss, contrP, done, out);
  else
    k_rowfinal<1><<<B_N / 4, 256, 0, stream>>>(rse, en, e8, T, labels, hist,
                                               celoss, contrP, done, out);
}